// Round 1
// baseline (81.592 us; speedup 1.0000x reference)
//
#include <hip/hip_runtime.h>

#define NCH 64
#define PMAX 1024
#define IMG 256
#define KSEL 8

__global__ __launch_bounds__(256) void raster_blend_kernel(
    const float* __restrict__ pts3D,  // [B, P, 3]
    const float* __restrict__ src,    // [B, C, P]
    float* __restrict__ out,          // [B, C, H, W]
    int P)
{
    const int h = blockIdx.x;   // row
    const int b = blockIdx.y;   // batch
    const int w = threadIdx.x;  // column (0..255)
    const int HW = IMG * IMG;

    const float r_ndc  = (1.5f / (float)IMG) * 2.0f;
    const float r2     = r_ndc * r_ndc;
    const float inv_r2 = 1.0f / r2;

    const float yf = 1.0f - (2.0f * (float)h + 1.0f) / (float)IMG;
    const float xf = 1.0f - (2.0f * (float)w + 1.0f) / (float)IMG;

    __shared__ float cx[PMAX];
    __shared__ float cy[PMAX];
    __shared__ float cz[PMAX];
    __shared__ int   ci[PMAX];
    __shared__ int   cnt;
    if (w == 0) cnt = 0;
    __syncthreads();

    // ---- Phase 1: row-filter all points into LDS candidate list ----
    // Point covers some pixel in this row only if dy^2 <= r^2 (necessary cond).
    const float* pb = pts3D + (size_t)b * P * 3;
    for (int p = w; p < P; p += 256) {
        float px = -pb[p * 3 + 0];   // reference negates x
        float py = -pb[p * 3 + 1];   // reference negates y
        float pz =  pb[p * 3 + 2];
        float dy = yf - py;
        if (dy * dy <= r2 && pz > 0.0f) {
            int slot = atomicAdd(&cnt, 1);
            cx[slot] = px;
            cy[slot] = py;
            cz[slot] = pz;
            ci[slot] = p;
        }
    }
    __syncthreads();
    const int n = cnt;

    // ---- Phase 2: per-pixel K-nearest-in-z selection (register insertion) ----
    const float SENT = 1e30f;  // z is in [0.1, 2.0]; sentinel = empty slot
    float zb[KSEL];
    float db[KSEL];
    int   ib[KSEL];
#pragma unroll
    for (int s = 0; s < KSEL; ++s) { zb[s] = SENT; db[s] = 0.0f; ib[s] = 0; }

#pragma unroll 1
    for (int j = 0; j < n; ++j) {
        float dx = xf - cx[j];
        float dy = yf - cy[j];
        float d2 = fmaf(dx, dx, dy * dy);
        float z  = cz[j];
        if (d2 <= r2 && z < zb[KSEL - 1]) {
            float carz = z, card = d2;
            int   cari = ci[j];
#pragma unroll
            for (int s = 0; s < KSEL; ++s) {
                if (carz < zb[s]) {
                    float tz = zb[s]; zb[s] = carz; carz = tz;
                    float td = db[s]; db[s] = card; card = td;
                    int   ti = ib[s]; ib[s] = cari; cari = ti;
                }
            }
        }
    }

    // ---- Epilogue: alpha-composite weights (front-to-back) ----
    float wk[KSEL];
    float T = 1.0f;
#pragma unroll
    for (int s = 0; s < KSEL; ++s) {
        bool valid = zb[s] < 1e29f;
        float dn = db[s] * inv_r2;
        dn = fminf(fmaxf(dn, 0.001f), 1.0f);
        float a = 1.0f - sqrtf(dn);
        a = valid ? a : 0.0f;
        wk[s] = a * T;
        T *= (1.0f - a);
    }

    // ---- Channel accumulation: k-outer, wave-level skip of empty k ----
    float acc[NCH];
#pragma unroll
    for (int c = 0; c < NCH; ++c) acc[c] = 0.0f;

    const float* sb = src + (size_t)b * NCH * P;
#pragma unroll
    for (int k = 0; k < KSEL; ++k) {
        bool valid = zb[k] < 1e29f;
        if (__any(valid)) {
            float wv = wk[k];            // 0 for invalid lanes
            const float* sp = sb + ib[k];  // ib=0 for invalid lanes (harmless)
#pragma unroll
            for (int c = 0; c < NCH; ++c)
                acc[c] = fmaf(wv, sp[(size_t)c * P], acc[c]);
        }
    }

    // ---- Store: 64 coalesced per-channel stores ----
    float* op = out + (size_t)b * NCH * HW + (size_t)h * IMG + w;
#pragma unroll
    for (int c = 0; c < NCH; ++c)
        op[(size_t)c * HW] = acc[c];
}

extern "C" void kernel_launch(void* const* d_in, const int* in_sizes, int n_in,
                              void* d_out, int out_size, void* d_ws, size_t ws_size,
                              hipStream_t stream) {
    const float* pts3D = (const float*)d_in[0];
    const float* src   = (const float*)d_in[1];
    float* out = (float*)d_out;

    // out_size = B * C * H * W
    const int B = out_size / (NCH * IMG * IMG);
    const int P = in_sizes[0] / (3 * B);

    dim3 grid(IMG, B, 1);
    dim3 block(IMG, 1, 1);
    raster_blend_kernel<<<grid, block, 0, stream>>>(pts3D, src, out, P);
}

// Round 2
// 73.991 us; speedup vs baseline: 1.1027x; 1.1027x over previous
//
#include <hip/hip_runtime.h>

#define NCH 64
#define IMG 256
#define KSEL 8
#define CAP 128          // max candidates per row (mean ~12, sd ~3.4; 128 is ~30 sd)
#define FPAD 17          // float4 per candidate slot (= 68 floats; pad vs 16 to break banks)

// ---- pre-kernel: src [B,C,P] -> srcT [B,P,C] so feature vectors are contiguous ----
__global__ __launch_bounds__(256) void transpose_src_kernel(
    const float* __restrict__ src, float* __restrict__ srcT, int P, int total)
{
    int t = blockIdx.x * 256 + threadIdx.x;
    if (t >= total) return;
    int p  = t % P;
    int bc = t / P;
    int c  = bc & (NCH - 1);
    int b  = bc >> 6;               // NCH = 64
    srcT[((size_t)(b * P + p)) * NCH + c] = src[t];
}

__global__ __launch_bounds__(256) void raster_blend_kernel(
    const float* __restrict__ pts3D,  // [B, P, 3]
    const float* __restrict__ srcT,   // [B, P, C] (transposed, in ws)
    float* __restrict__ out,          // [B, C, H, W]
    int P)
{
    const int h = blockIdx.x;   // row
    const int b = blockIdx.y;   // batch
    const int w = threadIdx.x;  // column (0..255)
    const int HW = IMG * IMG;

    const float r_ndc  = (1.5f / (float)IMG) * 2.0f;
    const float r2     = r_ndc * r_ndc;
    const float inv_r2 = 1.0f / r2;

    const float yf = 1.0f - (2.0f * (float)h + 1.0f) / (float)IMG;
    const float xf = 1.0f - (2.0f * (float)w + 1.0f) / (float)IMG;

    __shared__ float cx[CAP];
    __shared__ float cy[CAP];
    __shared__ float cz[CAP];
    __shared__ int   ci[CAP];
    __shared__ int   cnt;
    __shared__ __align__(16) float featS[CAP * FPAD * 4];  // 34816 B
    if (w == 0) cnt = 0;
    __syncthreads();

    // ---- Phase 1: row-filter all points into LDS candidate list ----
    const float* pb = pts3D + (size_t)b * P * 3;
    for (int p = w; p < P; p += 256) {
        float px = -pb[p * 3 + 0];
        float py = -pb[p * 3 + 1];
        float pz =  pb[p * 3 + 2];
        float dy = yf - py;
        if (dy * dy <= r2 && pz > 0.0f) {
            int slot = atomicAdd(&cnt, 1);
            if (slot < CAP) {
                cx[slot] = px;
                cy[slot] = py;
                cz[slot] = pz;
                ci[slot] = p;
            }
        }
    }
    __syncthreads();
    const int n = min(cnt, CAP);

    // ---- Phase 1b: stage candidate feature vectors into LDS (coalesced) ----
    const float* sT = srcT + (size_t)b * P * NCH;
    for (int t = w; t < n * NCH; t += 256) {
        int j = t >> 6;          // candidate slot
        int c = t & 63;          // channel
        featS[j * (FPAD * 4) + c] = sT[(size_t)ci[j] * NCH + c];
    }

    // ---- Phase 2: per-pixel K-nearest-in-z selection (register insertion) ----
    const float SENT = 1e30f;
    float zb[KSEL];
    float db[KSEL];
    int   jb[KSEL];
#pragma unroll
    for (int s = 0; s < KSEL; ++s) { zb[s] = SENT; db[s] = 0.0f; jb[s] = 0; }

    for (int j = 0; j < n; ++j) {
        float dx = xf - cx[j];
        float dy = yf - cy[j];
        float d2 = fmaf(dx, dx, dy * dy);
        float z  = cz[j];
        if (d2 <= r2 && z < zb[KSEL - 1]) {
            float carz = z, card = d2;
            int   carj = j;
#pragma unroll
            for (int s = 0; s < KSEL; ++s) {
                if (carz < zb[s]) {
                    float tz = zb[s]; zb[s] = carz; carz = tz;
                    float td = db[s]; db[s] = card; card = td;
                    int   tj = jb[s]; jb[s] = carj; carj = tj;
                }
            }
        }
    }

    // ---- weights: alpha-composite front-to-back ----
    float wk[KSEL];
    bool  vk[KSEL];
    float T = 1.0f;
#pragma unroll
    for (int s = 0; s < KSEL; ++s) {
        bool valid = zb[s] < 1e29f;
        vk[s] = valid;
        float dn = db[s] * inv_r2;
        dn = fminf(fmaxf(dn, 0.001f), 1.0f);
        float a = 1.0f - sqrtf(dn);
        a = valid ? a : 0.0f;
        wk[s] = a * T;
        T *= (1.0f - a);
    }

    __syncthreads();   // staging complete before feat reads

    // ---- channel accumulation from LDS feature cache ----
    float4 acc[NCH / 4];
#pragma unroll
    for (int c4 = 0; c4 < NCH / 4; ++c4) acc[c4] = make_float4(0.f, 0.f, 0.f, 0.f);

    const float4* fv = (const float4*)featS;
#pragma unroll
    for (int k = 0; k < KSEL; ++k) {
        if (__any(vk[k])) {
            float wv = wk[k];                       // 0 for invalid lanes
            const float4* fp = fv + jb[k] * FPAD;   // jb=0 safe (n>=1 if any valid)
#pragma unroll
            for (int c4 = 0; c4 < NCH / 4; ++c4) {
                float4 f = fp[c4];
                acc[c4].x = fmaf(wv, f.x, acc[c4].x);
                acc[c4].y = fmaf(wv, f.y, acc[c4].y);
                acc[c4].z = fmaf(wv, f.z, acc[c4].z);
                acc[c4].w = fmaf(wv, f.w, acc[c4].w);
            }
        }
    }

    // ---- store: 64 coalesced per-channel dword stores ----
    float* op = out + (size_t)b * NCH * HW + (size_t)h * IMG + w;
#pragma unroll
    for (int c4 = 0; c4 < NCH / 4; ++c4) {
        op[(size_t)(4 * c4 + 0) * HW] = acc[c4].x;
        op[(size_t)(4 * c4 + 1) * HW] = acc[c4].y;
        op[(size_t)(4 * c4 + 2) * HW] = acc[c4].z;
        op[(size_t)(4 * c4 + 3) * HW] = acc[c4].w;
    }
}

extern "C" void kernel_launch(void* const* d_in, const int* in_sizes, int n_in,
                              void* d_out, int out_size, void* d_ws, size_t ws_size,
                              hipStream_t stream) {
    const float* pts3D = (const float*)d_in[0];
    const float* src   = (const float*)d_in[1];
    float* out  = (float*)d_out;
    float* srcT = (float*)d_ws;

    const int B = out_size / (NCH * IMG * IMG);
    const int P = in_sizes[0] / (3 * B);

    const int total = B * NCH * P;
    transpose_src_kernel<<<(total + 255) / 256, 256, 0, stream>>>(src, srcT, P, total);

    dim3 grid(IMG, B, 1);
    dim3 block(IMG, 1, 1);
    raster_blend_kernel<<<grid, block, 0, stream>>>(pts3D, srcT, out, P);
}